// Round 12
// baseline (78.448 us; speedup 1.0000x reference)
//
#include <hip/hip_runtime.h>

#define NJ 8
#define TS 2048
#define NB 1024
#define CHUNK 256               // 64 lanes * 4 steps per wave-scan
#define NCH (TS / CHUNK)        // 8
#define DTC (1.0f / 60.0f)

// DPP cross-lane move, all-VALU (no DS pipe). CTRL: row_shr:N = 0x110+N,
// row_bcast15 = 0x142, row_bcast31 = 0x143.
template<int CTRL>
__device__ __forceinline__ float dppf(float v) {
    return __int_as_float(__builtin_amdgcn_update_dpp(
        __float_as_int(v), __float_as_int(v), CTRL, 0xF, 0xF, false));
}

#define ROUND(CTRL, COND) do {                                          \
    float o_r0 = dppf<CTRL>(r0), o_r1 = dppf<CTRL>(r1),                 \
          o_rc = dppf<CTRL>(rc), o_s0 = dppf<CTRL>(s0),                 \
          o_s1 = dppf<CTRL>(s1), o_sc = dppf<CTRL>(sc);                 \
    if (COND) {                                                         \
        float nr0 = fmaf(r0, o_s0, r1 * o_r0);                          \
        float nr1 = fmaf(r0, o_s1, r1 * o_r1);                          \
        float nrc = fmaf(r0, o_sc, fmaf(r1, o_rc, rc));                 \
        float ns0 = fmaf(s0, o_s0, s1 * o_r0);                          \
        float ns1 = fmaf(s0, o_s1, s1 * o_r1);                          \
        float nsc = fmaf(s0, o_sc, fmaf(s1, o_rc, sc));                 \
        r0 = nr0; r1 = nr1; rc = nrc; s0 = ns0; s1 = ns1; sc = nsc;     \
    } } while (0)

// lgkm-only barrier: syncs waves + LDS visibility WITHOUT draining vmcnt,
// so global loads pipeline freely across chunk periods.
__device__ __forceinline__ void lgkm_barrier() {
    asm volatile("s_waitcnt lgkmcnt(0)" ::: "memory");
    __builtin_amdgcn_s_barrier();
    __builtin_amdgcn_sched_barrier(0);
}

__global__ __launch_bounds__(512, 4) void phys_direct_kernel(
    const float4* __restrict__ x,       // (B,T,8) as float4 per (t,joint)
    const float*  __restrict__ state0,  // (B,8,2)
    const float*  __restrict__ M,       // (8,2)
    const float*  __restrict__ inertia, // (8,)
    const float*  __restrict__ damping, // (8,)
    float* __restrict__ out,            // (B,T,8)
    float* __restrict__ muscle,         // (B,8,2,2)
    float* __restrict__ finals)         // (B,8,2)
{
    __shared__ float4 tb[2][CHUNK * NJ / 4];   // 2 x 8 KB theta transpose dbuf

    const int b    = blockIdx.x;
    const int tid  = threadIdx.x;
    const int j    = tid >> 6;          // wave id = joint index
    const int lane = tid & 63;

    const float M0  = M[j * 2 + 0];
    const float M1  = M[j * 2 + 1];
    const float M20 = M0 * M0;
    const float M21 = M1 * M1;
    const float d   = damping[j];
    const float p   = DTC / inertia[j];      // DT / I
    const float gd  = 1.0f - p * d;          // dθ self-coefficient

    float thc  = state0[(b * NJ + j) * 2 + 0];
    float dthc = state0[(b * NJ + j) * 2 + 1];

    // input: float4 (t, j) at index t*8 + j. Lane owns steps 4*lane..4*lane+3.
    const float4* xb = x + (size_t)b * TS * NJ;
    const int lbase = 32 * lane + j;

    // register double-buffer of the 4 per-lane input float4s
    float4 cv[4], nv[4];
    #pragma unroll
    for (int k = 0; k < 4; ++k) cv[k] = xb[lbase + 8 * k];

    float4* outf4 = (float4*)out + (size_t)b * TS * 2;   // 2 float4 per row

    for (int ch = 0; ch <= NCH; ++ch) {
        // sync point: tout(ch-1) visible, tout buffers safe to swap.
        // vmcnt NOT drained — in-flight loads ride through.
        lgkm_barrier();

        // issue next chunk's loads immediately (consumed one period later)
        if (ch + 1 < NCH) {
            #pragma unroll
            for (int k = 0; k < 4; ++k)
                nv[k] = xb[(ch + 1) * (CHUNK * NJ) + lbase + 8 * k];
        }

        // ---- store phase: coalesced float4 write-out of chunk ch-1 ----
        // tout word w stored at w ^ ((w>>6)&31). Output float4 f covers
        // words 4f+c; m=(f>>4)&31 uniform over c; block q=f^(m>>2);
        // components permuted by pm=m&3.  (verified R6)
        if (ch > 0) {
            const float4* tr = tb[(ch - 1) & 1];
            int f  = tid;
            int m  = (f >> 4) & 31;
            int pm = m & 3;
            float4 r = tr[f ^ (m >> 2)];
            float rx = r.x, ry = r.y, rz = r.z, rw = r.w;
            if (pm & 1) { float tq = rx; rx = ry; ry = tq; tq = rz; rz = rw; rw = tq; }
            if (pm & 2) { float tq = rx; rx = rz; rz = tq; tq = ry; ry = rw; rw = tq; }
            outf4[(size_t)(ch - 1) * (CHUNK / 2) * 4 + f] = make_float4(rx, ry, rz, rw);
        }

        if (ch < NCH) {
            float* tw = (float*)tb[ch & 1];

            // a,c for my 4 steps directly from registers
            float a[4], cc[4];
            #pragma unroll
            for (int k = 0; k < 4; ++k) {
                float4 v = cv[k];
                a[k]  = fmaf(M0,  v.x, M1  * v.y);   // einsum(M, F_t)
                cc[k] = fmaf(M20, v.z, M21 * v.w);   // einsum(M2, K_t)
            }

            // serially compose my 4 step-maps:
            //   dθ' = r0·θ + r1·dθ + rc ;  θ' = s0·θ + s1·dθ + sc
            float r0 = 0.0f, r1 = 1.0f, rc = 0.0f;   // identity
            float s0 = 1.0f, s1 = 0.0f, sc = 0.0f;
            #pragma unroll
            for (int k = 0; k < 4; ++k) {
                float pa = p * a[k];
                float pc = p * cc[k];
                float nr0 = fmaf(-pc, s0, gd * r0);
                float nr1 = fmaf(-pc, s1, gd * r1);
                float nrc = fmaf(-pc, sc, fmaf(gd, rc, pa));
                s0 = fmaf(DTC, nr0, s0);
                s1 = fmaf(DTC, nr1, s1);
                sc = fmaf(DTC, nrc, sc);
                r0 = nr0; r1 = nr1; rc = nrc;
            }

            // inclusive scan over 64 lanes — DPP wave-scan, all VALU
            ROUND(0x111, (lane & 15) >= 1);
            ROUND(0x112, (lane & 15) >= 2);
            ROUND(0x114, (lane & 15) >= 4);
            ROUND(0x118, (lane & 15) >= 8);
            ROUND(0x142, (lane & 31) >= 16);
            ROUND(0x143, lane >= 32);

            // end state after my steps = inclusive map applied to carry;
            // my start state = lane (l-1)'s end state, shifted up by 1.
            float th_e  = fmaf(s0, thc, fmaf(s1, dthc, sc));
            float dth_e = fmaf(r0, thc, fmaf(r1, dthc, rc));
            float th  = __shfl_up(th_e, 1, 64);
            float dth = __shfl_up(dth_e, 1, 64);
            if (lane == 0) { th = thc; dth = dthc; }

            // replay 4 steps in exact reference op-order; θ -> transpose buf.
            // word w = 32*lane + 8k + j; store at w ^ ((w>>6)&31)
            //        = w ^ ((lane>>1)&31)   (2 lanes/bank = free)
            const int wsig = (lane >> 1) & 31;
            #pragma unroll
            for (int k = 0; k < 4; ++k) {
                float u = fmaf(-cc[k], th, a[k]);    // a - c·θ
                u = fmaf(-d, dth, u);                // ... - d·dθ
                dth = fmaf(p, u, dth);
                th  = fmaf(DTC, dth, th);
                tw[(32 * lane + 8 * k + j) ^ wsig] = th;
            }

            // carry = lane 63's end state (uniform lane -> v_readlane)
            thc  = __shfl(th, 63, 64);
            dthc = __shfl(dth, 63, 64);

            // rotate register double-buffer (SSA-renamed, no real moves)
            #pragma unroll
            for (int k = 0; k < 4; ++k) cv[k] = nv[k];
        }
    }

    if (lane == 0) {
        const int idx = b * NJ + j;
        finals[idx * 2 + 0] = thc;
        finals[idx * 2 + 1] = dthc;
        muscle[idx * 4 + 0] = thc  * M0;
        muscle[idx * 4 + 1] = thc  * M1;
        muscle[idx * 4 + 2] = dthc * M0;
        muscle[idx * 4 + 3] = dthc * M1;
    }
}

extern "C" void kernel_launch(void* const* d_in, const int* in_sizes, int n_in,
                              void* d_out, int out_size, void* d_ws, size_t ws_size,
                              hipStream_t stream) {
    const float4* x      = (const float4*)d_in[0];
    const float*  state0 = (const float*)d_in[1];
    const float*  M      = (const float*)d_in[2];
    const float*  inertia= (const float*)d_in[3];
    const float*  damping= (const float*)d_in[4];

    float* out    = (float*)d_out;                       // (B,T,8)
    float* muscle = out + (size_t)NB * TS * NJ;          // (B,8,2,2)
    float* finals = muscle + (size_t)NB * NJ * 2 * 2;    // (B,8,2)

    dim3 block(512);          // 8 waves = 8 joints of one batch
    dim3 grid(NB);            // 1024 blocks = 4 blocks/CU, single generation
    phys_direct_kernel<<<grid, block, 0, stream>>>(x, state0, M, inertia, damping,
                                                   out, muscle, finals);
}

// Round 14
// 58.723 us; speedup vs baseline: 1.3359x; 1.3359x over previous
//
#include <hip/hip_runtime.h>

#define NJ 8
#define TS 2048
#define NB 1024
#define CHUNK 256               // 64 lanes * 4 steps per wave-scan
#define NCH (TS / CHUNK)        // 8
#define F4C (CHUNK * NJ)        // 2048 float4 = 32 KB per buffer
#define DTC (1.0f / 60.0f)

typedef float f32x4 __attribute__((ext_vector_type(4)));

// async global->LDS, 16B per lane. lds_base must be wave-uniform; HW writes
// lds_base + lane*16. Global src is per-lane.
__device__ __forceinline__ void dma16(const float4* g, float4* lds_base) {
#if __has_builtin(__builtin_amdgcn_global_load_lds)
    __builtin_amdgcn_global_load_lds(
        (const __attribute__((address_space(1))) void*)g,
        (__attribute__((address_space(3))) void*)lds_base,
        16, 0, 0);
#else
    lds_base[threadIdx.x & 63] = *g;
#endif
}

// DPP cross-lane move, all-VALU (no DS pipe). CTRL: row_shr:N = 0x110+N,
// row_bcast15 = 0x142, row_bcast31 = 0x143.
template<int CTRL>
__device__ __forceinline__ float dppf(float v) {
    return __int_as_float(__builtin_amdgcn_update_dpp(
        __float_as_int(v), __float_as_int(v), CTRL, 0xF, 0xF, false));
}

#define ROUND(CTRL, COND) do {                                          \
    float o_r0 = dppf<CTRL>(r0), o_r1 = dppf<CTRL>(r1),                 \
          o_rc = dppf<CTRL>(rc), o_s0 = dppf<CTRL>(s0),                 \
          o_s1 = dppf<CTRL>(s1), o_sc = dppf<CTRL>(sc);                 \
    if (COND) {                                                         \
        float nr0 = fmaf(r0, o_s0, r1 * o_r0);                          \
        float nr1 = fmaf(r0, o_s1, r1 * o_r1);                          \
        float nrc = fmaf(r0, o_sc, fmaf(r1, o_rc, rc));                 \
        float ns0 = fmaf(s0, o_s0, s1 * o_r0);                          \
        float ns1 = fmaf(s0, o_s1, s1 * o_r1);                          \
        float nsc = fmaf(s0, o_sc, fmaf(s1, o_rc, sc));                 \
        r0 = nr0; r1 = nr1; rc = nrc; s0 = ns0; s1 = ns1; sc = nsc;     \
    } } while (0)

__global__ __launch_bounds__(512, 4) void phys_nt_kernel(
    const float4* __restrict__ x,       // (B,T,8) as float4 per (t,joint)
    const float*  __restrict__ state0,  // (B,8,2)
    const float*  __restrict__ M,       // (8,2)
    const float*  __restrict__ inertia, // (8,)
    const float*  __restrict__ damping, // (8,)
    float* __restrict__ out,            // (B,T,8)
    float* __restrict__ muscle,         // (B,8,2,2)
    float* __restrict__ finals)         // (B,8,2)
{
    __shared__ float4 xin[2][F4C];           // 2 x 32 KB input double-buffer
    __shared__ float4 tb[2][CHUNK * NJ / 4]; // 2 x 8 KB theta transpose dbuf

    const int b    = blockIdx.x;
    const int tid  = threadIdx.x;
    const int j    = tid >> 6;          // wave id = joint index
    const int lane = tid & 63;

    const float M0  = M[j * 2 + 0];
    const float M1  = M[j * 2 + 1];
    const float M20 = M0 * M0;
    const float M21 = M1 * M1;
    const float d   = damping[j];
    const float p   = DTC / inertia[j];      // DT / I
    const float gd  = 1.0f - p * d;          // dθ self-coefficient

    float thc  = state0[(b * NJ + j) * 2 + 0];
    float dthc = state0[(b * NJ + j) * 2 + 1];

    const float4* xb = x + (size_t)b * TS * NJ;
    const int wv = j;   // wave index == joint

    // prologue: async-stage chunk 0.
    // dest idx (linear) = 512i + 64w + lane; src idx = dest ^ ((dest>>6)&7)
    //                   = 512i + 64w + (lane^w)   (pre-swizzled global source)
    {
        float4* lb = &xin[0][64 * wv];
        const float4* gb = xb + 64 * wv + (lane ^ wv);
        #pragma unroll
        for (int i = 0; i < 4; ++i) dma16(gb + 512 * i, lb + 512 * i);
    }

    for (int ch = 0; ch <= NCH; ++ch) {
        // single barrier per chunk: drains DMA(ch) [vmcnt] and makes
        // tout(ch-1) visible [lgkmcnt]; also buffer-overwrite safety.
        __syncthreads();

        // issue DMA for chunk ch+1 into the other xin buffer (full-chunk slack)
        if (ch + 1 < NCH) {
            float4* lb = &xin[(ch + 1) & 1][64 * wv];
            const float4* gb = xb + (size_t)(ch + 1) * F4C + 64 * wv + (lane ^ wv);
            #pragma unroll
            for (int i = 0; i < 4; ++i) dma16(gb + 512 * i, lb + 512 * i);
        }

        // ---- store phase: coalesced NON-TEMPORAL write-out of chunk ch-1 ----
        // nt: bypass cache allocation so L3 keeps the (L3-sized) input
        // resident across harness replays. Full-block dense rows: each wave
        // writes a contiguous 1-KB span, full 64-B lines.
        if (ch > 0) {
            const float4* tr = tb[(ch - 1) & 1];
            float* outc = out + ((size_t)b * TS + (size_t)(ch - 1) * CHUNK) * NJ;
            int f  = tid;
            int m  = (f >> 4) & 31;
            int pm = m & 3;
            float4 r = tr[f ^ (m >> 2)];
            float rx = r.x, ry = r.y, rz = r.z, rw = r.w;
            if (pm & 1) { float tq = rx; rx = ry; ry = tq; tq = rz; rz = rw; rw = tq; }
            if (pm & 2) { float tq = rx; rx = rz; rz = tq; tq = ry; ry = rw; rw = tq; }
            f32x4 val = { rx, ry, rz, rw };
            __builtin_nontemporal_store(val, ((f32x4*)outc) + f);
        }

        if (ch < NCH) {
            // ---- compute phase on xin[ch&1] ----
            const float4* xc = xin[ch & 1];
            float* tw = (float*)tb[ch & 1];

            // element (step s=4*lane+k, joint j): natural idx 32*lane+8k+j,
            // swizzle ^((idx>>6)&7) = ^((lane>>1)&7)
            float a[4], cc[4];
            const int base = 32 * lane + (j ^ ((lane >> 1) & 7));
            #pragma unroll
            for (int k = 0; k < 4; ++k) {
                float4 v = xc[base + 8 * k];
                a[k]  = fmaf(M0,  v.x, M1  * v.y);   // einsum(M, F_t)
                cc[k] = fmaf(M20, v.z, M21 * v.w);   // einsum(M2, K_t)
            }

            // serially compose my 4 step-maps:
            //   dθ' = r0·θ + r1·dθ + rc ;  θ' = s0·θ + s1·dθ + sc
            float r0 = 0.0f, r1 = 1.0f, rc = 0.0f;   // identity
            float s0 = 1.0f, s1 = 0.0f, sc = 0.0f;
            #pragma unroll
            for (int k = 0; k < 4; ++k) {
                float pa = p * a[k];
                float pc = p * cc[k];
                float nr0 = fmaf(-pc, s0, gd * r0);
                float nr1 = fmaf(-pc, s1, gd * r1);
                float nrc = fmaf(-pc, sc, fmaf(gd, rc, pa));
                s0 = fmaf(DTC, nr0, s0);
                s1 = fmaf(DTC, nr1, s1);
                sc = fmaf(DTC, nrc, sc);
                r0 = nr0; r1 = nr1; rc = nrc;
            }

            // inclusive scan over 64 lanes — DPP wave-scan, all VALU
            ROUND(0x111, (lane & 15) >= 1);
            ROUND(0x112, (lane & 15) >= 2);
            ROUND(0x114, (lane & 15) >= 4);
            ROUND(0x118, (lane & 15) >= 8);
            ROUND(0x142, (lane & 31) >= 16);
            ROUND(0x143, lane >= 32);

            // end state after my steps = inclusive map applied to carry;
            // my start state = lane (l-1)'s end state, shifted up by 1.
            float th_e  = fmaf(s0, thc, fmaf(s1, dthc, sc));
            float dth_e = fmaf(r0, thc, fmaf(r1, dthc, rc));
            float th  = __shfl_up(th_e, 1, 64);
            float dth = __shfl_up(dth_e, 1, 64);
            if (lane == 0) { th = thc; dth = dthc; }

            // replay 4 steps in exact reference op-order; θ -> transpose buf.
            // word w = 32*lane + 8k + j; store at w ^ ((w>>6)&31)
            //        = w ^ ((lane>>1)&31)   (2 lanes/bank = free)
            const int wsig = (lane >> 1) & 31;
            #pragma unroll
            for (int k = 0; k < 4; ++k) {
                float u = fmaf(-cc[k], th, a[k]);    // a - c·θ
                u = fmaf(-d, dth, u);                // ... - d·dθ
                dth = fmaf(p, u, dth);
                th  = fmaf(DTC, dth, th);
                tw[(32 * lane + 8 * k + j) ^ wsig] = th;
            }

            // carry = lane 63's end state (uniform lane -> v_readlane)
            thc  = __shfl(th, 63, 64);
            dthc = __shfl(dth, 63, 64);
        }
    }

    if (lane == 0) {
        const int idx = b * NJ + j;
        finals[idx * 2 + 0] = thc;
        finals[idx * 2 + 1] = dthc;
        muscle[idx * 4 + 0] = thc  * M0;
        muscle[idx * 4 + 1] = thc  * M1;
        muscle[idx * 4 + 2] = dthc * M0;
        muscle[idx * 4 + 3] = dthc * M1;
    }
}

extern "C" void kernel_launch(void* const* d_in, const int* in_sizes, int n_in,
                              void* d_out, int out_size, void* d_ws, size_t ws_size,
                              hipStream_t stream) {
    const float4* x      = (const float4*)d_in[0];
    const float*  state0 = (const float*)d_in[1];
    const float*  M      = (const float*)d_in[2];
    const float*  inertia= (const float*)d_in[3];
    const float*  damping= (const float*)d_in[4];

    float* out    = (float*)d_out;                       // (B,T,8)
    float* muscle = out + (size_t)NB * TS * NJ;          // (B,8,2,2)
    float* finals = muscle + (size_t)NB * NJ * 2 * 2;    // (B,8,2)

    dim3 block(512);          // 8 waves = 8 joints of one batch
    dim3 grid(NB);            // 1024 blocks
    phys_nt_kernel<<<grid, block, 0, stream>>>(x, state0, M, inertia, damping,
                                               out, muscle, finals);
}